// Round 1
// 359.350 us; speedup vs baseline: 1.1201x; 1.1201x over previous
//
#include <hip/hip_runtime.h>
#include <hip/hip_bf16.h>
#include <cstddef>

#define NB 32
#define CC 64
#define TT 16
#define VV 256
#define KK 5

typedef __attribute__((ext_vector_type(8))) short short8;
typedef __attribute__((ext_vector_type(4))) float f32x4;

union U16B { short8 s8; uint2 u2[2]; uint4 u4; unsigned u[4]; unsigned short us[8]; };

__device__ inline unsigned short f2bf(float f) {
    unsigned u = __float_as_uint(f);
    return (unsigned short)((u + 0x7fffu + ((u >> 16) & 1u)) >> 16);
}
// packed bf16 convert (RNE, same rounding as f2bf): low = a, high = b
__device__ inline unsigned cvtpk(float a, float b) {
    unsigned r;
    asm("v_cvt_pk_bf16_f32 %0, %1, %2" : "=v"(r) : "v"(a), "v"(b));
    return r;
}

// ---------------------------------------------------------------------------
// K1: pure vectorized copy A -> out tail (degree sums now computed in k_fuse).
__global__ __launch_bounds__(256) void k_copyA(const float4* __restrict__ A4,
                                               float4* __restrict__ outA4)
{
    int n = blockIdx.x, rb = blockIdx.y, t = threadIdx.x;
    // per n: 1280 rows x 64 float4; per block: 32 rows
    size_t base = (size_t)n * (KK * VV * VV / 4) + (size_t)rb * (32 * 64)
                + (size_t)(t >> 6) * (8 * 64) + (t & 63);
#pragma unroll
    for (int i = 0; i < 8; i++)
        outA4[base + i * 64] = A4[base + i * 64];
}

// ---------------------------------------------------------------------------
// K2: xcb[n,c,t,v] = bf16( sum_ci Wc[c,ci]*x[n,ci,t,v] + bc[c] )
__global__ __launch_bounds__(256) void k_xc(const float* __restrict__ x,
                                            const float* __restrict__ Wc,
                                            const float* __restrict__ bc,
                                            __hip_bfloat16* __restrict__ xcb)
{
    __shared__ float WT[64 * 64];  // WT[ci][co]
    __shared__ float bs[64];
    int n = blockIdx.x, tid = threadIdx.x;
    int p = blockIdx.y * 256 + tid;  // t*256+v index
    for (int i = tid; i < 4096; i += 256) WT[(i & 63) * 64 + (i >> 6)] = Wc[i];
    if (tid < 64) bs[tid] = bc[tid];
    __syncthreads();

    float acc[64];
#pragma unroll
    for (int c = 0; c < 64; c++) acc[c] = bs[c];
#pragma unroll 4
    for (int ci = 0; ci < 64; ci++) {
        float xv = x[((size_t)n * 64 + ci) * 4096 + p];
        const float4* wr = (const float4*)&WT[ci * 64];
#pragma unroll
        for (int q = 0; q < 16; q++) {
            float4 w4 = wr[q];
            acc[q * 4 + 0] = fmaf(w4.x, xv, acc[q * 4 + 0]);
            acc[q * 4 + 1] = fmaf(w4.y, xv, acc[q * 4 + 1]);
            acc[q * 4 + 2] = fmaf(w4.z, xv, acc[q * 4 + 2]);
            acc[q * 4 + 3] = fmaf(w4.w, xv, acc[q * 4 + 3]);
        }
    }
#pragma unroll
    for (int c = 0; c < 64; c++)
        xcb[((size_t)n * 64 + c) * 4096 + p] = __float2bfloat16(acc[c]);
}

// ---------------------------------------------------------------------------
// K3 fused: per block (n, 16-w tile). Per 16-v chunk:
//  Phase A: MLP -> M tile [64c][16w][16v] bf16 in LDS (M' never hits HBM)
//  Phase B: acc[c][t,w] += xcb . M via mfma (K upper half nulled via zero-block)
// Degree-norm dl[w] is factored out of the v-sum and applied in the epilogue.
// LDS: 16B zero block + per-wave h1/h2 transpose slices + M tile = 80,912 B
#define H1RS 48
#define H2RS 72
#define HWAVE (64 * H1RS + 64 * H2RS)      // 7680
#define MS_WST 48                          // 16 v * 2B + 16 pad (16*odd -> uniform)
#define MS_CST (16 * MS_WST + 16)          // 784
#define LDS_H0 16
#define LDS_MS (LDS_H0 + 4 * HWAVE)        // 30736
#define LDS_TOTAL (LDS_MS + 64 * MS_CST)   // 80912

__global__ __launch_bounds__(256) void k_fuse(
    const float* __restrict__ A, const float* __restrict__ hm,
    const __hip_bfloat16* __restrict__ xcb,
    const float* __restrict__ nh_w1, const float* __restrict__ nh_b1,
    const float* __restrict__ nh_w2, const float* __restrict__ nh_b2,
    const float* __restrict__ nh_w3, const float* __restrict__ nh_b3,
    const float* __restrict__ h_w1, const float* __restrict__ h_b1,
    const float* __restrict__ h_w2, const float* __restrict__ h_b2,
    const float* __restrict__ h_w3, const float* __restrict__ h_b3,
    float* __restrict__ out)
{
    __shared__ char smem[LDS_TOTAL];
    int tid = threadIdx.x, lane = tid & 63, wid = tid >> 6;
    int n = blockIdx.x, wt = blockIdx.y;
    int col = lane & 15, quad = lane >> 4;
    int vl = col;  // Phase A lane role: point (w = wid*4+quad, v-local=vl)

    char* h1b = smem + LDS_H0 + wid * HWAVE;
    char* h2b = h1b + 64 * H1RS;

    if (tid < 4) ((unsigned*)smem)[tid] = 0;  // shared 16B zero block

    int w_lane = wt * 16 + wid * 4 + quad;
    bool flag_lane = hm[n * 256 + w_lane] > 0.5f;

    // group (per-pt) branch flags (wave-uniform)
    bool fg[4];
#pragma unroll
    for (int g = 0; g < 4; g++)
        fg[g] = hm[n * 256 + wt * 16 + wid * 4 + g] > 0.5f;

    // --- weight fragments for BOTH branches (VGPR-resident, loaded once) ---
    U16B w2u_n[2], w2u_h[2], w3u_n[4], w3u_h[4];
    f32x4 b2f_n[2], b2f_h[2];
    float b3c_n[4], b3c_h[4];
#pragma unroll
    for (int ot = 0; ot < 2; ot++) {
#pragma unroll
        for (int j = 0; j < 8; j++) {
            int k = quad * 8 + j;
            w2u_n[ot].us[j] = (k < 16) ? f2bf(nh_w2[(ot * 16 + col) * 16 + k]) : (unsigned short)0;
            w2u_h[ot].us[j] = (k < 16) ? f2bf(h_w2[(ot * 16 + col) * 16 + k]) : (unsigned short)0;
        }
#pragma unroll
        for (int r = 0; r < 4; r++) {
            b2f_n[ot][r] = nh_b2[ot * 16 + quad * 4 + r];
            b2f_h[ot][r] = h_b2[ot * 16 + quad * 4 + r];
        }
    }
#pragma unroll
    for (int ot = 0; ot < 4; ot++) {
#pragma unroll
        for (int j = 0; j < 8; j++) {
            w3u_n[ot].us[j] = f2bf(nh_w3[(ot * 16 + col) * 32 + quad * 8 + j]);
            w3u_h[ot].us[j] = f2bf(h_w3[(ot * 16 + col) * 32 + quad * 8 + j]);
        }
        // L3 swapped-operand output: lane's channel is ot*16+col -> scalar bias
        b3c_n[ot] = nh_b3[ot * 16 + col];
        b3c_h[ot] = h_b3[ot * 16 + col];
    }

    f32x4 acc[16];
#pragma unroll
    for (int i = 0; i < 16; i++) acc[i] = f32x4{0.f, 0.f, 0.f, 0.f};

    float asum = 0.f;  // per-lane partial of sum_{k,v} A[n,k,v,w_lane]

    __syncthreads();  // zero block visible

    // prefetch A for vc=0
    float a_cur[5];
#pragma unroll
    for (int k = 0; k < 5; k++)
        a_cur[k] = A[(((size_t)n * 5 + k) * 256 + vl) * 256 + w_lane];

    for (int vc = 0; vc < 16; vc++) {
        // ================= Phase A: MLP -> M-LDS =================
        {
            float a[5];
#pragma unroll
            for (int k = 0; k < 5; k++) { a[k] = a_cur[k]; asum += a[k]; }

            // prefetch next vc's A values (in flight across pt-loop + Phase B)
            if (vc < 15) {
                int v = (vc + 1) * 16 + vl;
#pragma unroll
                for (int k = 0; k < 5; k++)
                    a_cur[k] = A[(((size_t)n * 5 + k) * 256 + v) * 256 + w_lane];
            }

            float h1s[16];
#pragma unroll
            for (int o = 0; o < 16; o++) {
                float sn = nh_b1[o], sh = h_b1[o];
#pragma unroll
                for (int k = 0; k < 5; k++) {
                    sn = fmaf(nh_w1[o * 5 + k], a[k], sn);
                    sh = fmaf(h_w1[o * 5 + k], a[k], sh);
                }
                h1s[o] = flag_lane ? fmaxf(sh, 0.f) : fmaxf(sn, 0.f);
            }
            uint4 q0, q1;
            q0.x = cvtpk(h1s[0], h1s[1]);   q0.y = cvtpk(h1s[2], h1s[3]);
            q0.z = cvtpk(h1s[4], h1s[5]);   q0.w = cvtpk(h1s[6], h1s[7]);
            q1.x = cvtpk(h1s[8], h1s[9]);   q1.y = cvtpk(h1s[10], h1s[11]);
            q1.z = cvtpk(h1s[12], h1s[13]); q1.w = cvtpk(h1s[14], h1s[15]);
            *(uint4*)(h1b + lane * H1RS) = q0;
            *(uint4*)(h1b + lane * H1RS + 16) = q1;

#pragma unroll
            for (int pt = 0; pt < 4; pt++) {
                int row = pt * 16 + col;
                U16B af1;
                {
                    const char* p1 = (quad < 2) ? (h1b + row * H1RS + quad * 16) : smem;
                    af1.u4 = *(const uint4*)p1;
                }
                // L2+L3 body with branch-selected (wave-uniform) weight sets.
                // L3 uses SWAPPED operand order -> lane holds
                // M'[c=ot*16+col][w=wid*4+pt][v=quad*4+r] => one packed b64 store.
                auto body = [&](const U16B (&w2u)[2], const f32x4 (&b2f)[2],
                                const U16B (&w3u)[4], const float (&b3c)[4]) {
                    f32x4 a0 = b2f[0], a1 = b2f[1];
                    a0 = __builtin_amdgcn_mfma_f32_16x16x32_bf16(af1.s8, w2u[0].s8, a0, 0, 0, 0);
                    a1 = __builtin_amdgcn_mfma_f32_16x16x32_bf16(af1.s8, w2u[1].s8, a1, 0, 0, 0);
                    uint2 pk;
                    pk.x = cvtpk(fmaxf(a0[0], 0.f), fmaxf(a0[1], 0.f));
                    pk.y = cvtpk(fmaxf(a0[2], 0.f), fmaxf(a0[3], 0.f));
                    *(uint2*)(h2b + row * H2RS + quad * 8) = pk;
                    pk.x = cvtpk(fmaxf(a1[0], 0.f), fmaxf(a1[1], 0.f));
                    pk.y = cvtpk(fmaxf(a1[2], 0.f), fmaxf(a1[3], 0.f));
                    *(uint2*)(h2b + row * H2RS + 32 + quad * 8) = pk;
                    U16B af2;
                    af2.u2[0] = *(const uint2*)(h2b + row * H2RS + quad * 16);
                    af2.u2[1] = *(const uint2*)(h2b + row * H2RS + quad * 16 + 8);
#pragma unroll
                    for (int ot = 0; ot < 4; ot++) {
                        f32x4 a3 = f32x4{b3c[ot], b3c[ot], b3c[ot], b3c[ot]};
                        a3 = __builtin_amdgcn_mfma_f32_16x16x32_bf16(w3u[ot].s8, af2.s8, a3, 0, 0, 0);
                        uint2 mv;
                        mv.x = cvtpk(fmaxf(a3[0], 0.f), fmaxf(a3[1], 0.f));
                        mv.y = cvtpk(fmaxf(a3[2], 0.f), fmaxf(a3[3], 0.f));
                        *(uint2*)(smem + LDS_MS + (ot * 16 + col) * MS_CST +
                                  (wid * 4 + pt) * MS_WST + quad * 8) = mv;
                    }
                };
                if (fg[pt]) body(w2u_h, b2f_h, w3u_h, b3c_h);
                else        body(w2u_n, b2f_n, w3u_n, b3c_n);
            }
        }
        __syncthreads();  // M tile ready
        // ================= Phase B: contraction =================
        {
            const short* xbase = (const short*)xcb +
                (((size_t)n * 64) * 16 + col) * 256 + vc * 16 + (quad & 1) * 8;
#pragma unroll
            for (int cl = 0; cl < 16; cl++) {
                int c = wid * 16 + cl;
                short8 af = *(const short8*)(xbase + (size_t)c * 4096);
                const char* bp = (quad < 2)
                    ? (const char*)(smem + LDS_MS + c * MS_CST + col * MS_WST + quad * 16)
                    : (const char*)smem;  // zero block nulls k>=16
                U16B bf; bf.u4 = *(const uint4*)bp;
                acc[cl] = __builtin_amdgcn_mfma_f32_16x16x32_bf16(af, bf.s8, acc[cl], 0, 0, 0);
            }
        }
        __syncthreads();  // before next vc overwrites M
    }

    // ---- degree norm: reduce asum over the 16 col-lanes (same w per group) ----
    float s = asum;
    s += __shfl_xor(s, 1);
    s += __shfl_xor(s, 2);
    s += __shfl_xor(s, 4);
    s += __shfl_xor(s, 8);
    float* dls = (float*)(smem + LDS_H0);  // h regions dead; reuse 64 B
    if (col == 0) dls[wid * 4 + quad] = 1.f / (s + 0.001f);
    __syncthreads();
    float dlw = dls[col];  // epilogue lane's w = wt*16+col

    // epilogue: D col = w, rows quad*4+r = t (R3-verified convention)
#pragma unroll
    for (int cl = 0; cl < 16; cl++) {
        int c = wid * 16 + cl;
#pragma unroll
        for (int r = 0; r < 4; r++)
            out[(((size_t)n * 64 + c) * 16 + quad * 4 + r) * 256 + wt * 16 + col] =
                acc[cl][r] * dlw;
    }
}

// ---------------------------------------------------------------------------
extern "C" void kernel_launch(void* const* d_in, const int* in_sizes, int n_in,
                              void* d_out, int out_size, void* d_ws, size_t ws_size,
                              hipStream_t stream)
{
    const float* x      = (const float*)d_in[0];
    const float* A      = (const float*)d_in[1];
    const float* hmask  = (const float*)d_in[2];
    const float* conv_w = (const float*)d_in[4];
    const float* conv_b = (const float*)d_in[5];
    const float* nh_w1 = (const float*)d_in[6];
    const float* nh_b1 = (const float*)d_in[7];
    const float* nh_w2 = (const float*)d_in[8];
    const float* nh_b2 = (const float*)d_in[9];
    const float* nh_w3 = (const float*)d_in[10];
    const float* nh_b3 = (const float*)d_in[11];
    const float* h_w1 = (const float*)d_in[12];
    const float* h_b1 = (const float*)d_in[13];
    const float* h_w2 = (const float*)d_in[14];
    const float* h_b2 = (const float*)d_in[15];
    const float* h_w3 = (const float*)d_in[16];
    const float* h_b3 = (const float*)d_in[17];

    float* out  = (float*)d_out;
    float* outA = out + (size_t)NB * CC * TT * VV;

    __hip_bfloat16* xcb = (__hip_bfloat16*)d_ws;  // 16.8 MB

    k_copyA<<<dim3(NB, 40), 256, 0, stream>>>((const float4*)A, (float4*)outA);
    k_xc<<<dim3(NB, 16), 256, 0, stream>>>(x, conv_w, conv_b, xcb);
    k_fuse<<<dim3(NB, 16), 256, 0, stream>>>(
        A, hmask, xcb,
        nh_w1, nh_b1, nh_w2, nh_b2, nh_w3, nh_b3,
        h_w1, h_b1, h_w2, h_b2, h_w3, h_b3, out);
}